// Round 9
// baseline (817.606 us; speedup 1.0000x reference)
//
#include <hip/hip_runtime.h>

typedef unsigned short u16;
typedef unsigned int u32;
typedef __attribute__((ext_vector_type(8))) short short8;
typedef __attribute__((ext_vector_type(4))) float f32x4;

#define NB 2048
#define NTOK 49
#define CH 384
#define NH 12
#define HD 32
#define SCALE_Q 0.17677669529663687f
#define TABF 1956864   // 768 * 49 * 52

__device__ __forceinline__ u16 f2bf(float f) {
  u32 u = __float_as_uint(f);
  u += 0x7fffu + ((u >> 16) & 1u);
  return (u16)(u >> 16);
}
__device__ __forceinline__ float bf2f(u16 h) { return __uint_as_float(((u32)h) << 16); }
__device__ __forceinline__ u32 pk2(float a, float b) { return (u32)f2bf(a) | ((u32)f2bf(b) << 16); }

// async global->LDS, 16B per lane, LDS dest = wave-uniform base + lane*16
__device__ __forceinline__ void gload16(const u16* g, u16* l) {
  __builtin_amdgcn_global_load_lds(
      (const __attribute__((address_space(1))) u32*)g,
      (__attribute__((address_space(3))) u32*)l,
      16, 0, 0);
}

// ---------- prep_w: transpose weights to bf16 ----------
__global__ void prep_w(const float* __restrict__ w_qkv, const float* __restrict__ w_proj,
                       u16* __restrict__ wqkvT, u16* __restrict__ wprojT)
{
  int idx = blockIdx.x * 256 + threadIdx.x;
  if (idx < 1152 * 384) {
    int n = idx / 384, k = idx - n * 384;
    wqkvT[idx] = f2bf(w_qkv[(size_t)k * 1152 + n]);
  } else if (idx < 1152 * 384 + 384 * 384) {
    int i2 = idx - 1152 * 384;
    int n = i2 / 384, k = i2 - n * 384;
    wprojT[i2] = f2bf(w_proj[(size_t)k * 384 + n]);
  }
}

// ---------- prep_c: combined bias tables comb[p][wb][h][i][52] = rpb + mask ----------
__global__ __launch_bounds__(256) void prep_c(const float* __restrict__ rpb_table,
                                              const int* __restrict__ rel_index,
                                              const float* __restrict__ mask1,
                                              const float* __restrict__ mask2,
                                              float* __restrict__ comb)
{
  const int wbh = blockIdx.x;            // 0..767 = wb*12 + h
  const int wb = wbh / 12, h = wbh - wb * 12;
  const size_t ob = (size_t)wbh * (49 * 52);
  for (int r = threadIdx.x; r < 2401; r += 256) {
    int i = r / 49, j = r - i * 49;
    float rv = rpb_table[(size_t)rel_index[r] * 12 + h];
    comb[ob + i * 52 + j]        = rv + mask1[(size_t)wb * 2401 + r];
    comb[TABF + ob + i * 52 + j] = rv + mask2[(size_t)wb * 2401 + r];
  }
}

// ---------- convert x1,x2 f32 -> bf16 (8 elems/thread) ----------
__global__ __launch_bounds__(256) void conv_bf16(const float* __restrict__ x1, const float* __restrict__ x2,
                                                 u16* __restrict__ xb1, u16* __restrict__ xb2)
{
  const size_t i = ((size_t)blockIdx.x * 256 + threadIdx.x) * 8;
  float4 a = *reinterpret_cast<const float4*>(x1 + i);
  float4 b = *reinterpret_cast<const float4*>(x1 + i + 4);
  uint4 o;
  o.x = pk2(a.x, a.y); o.y = pk2(a.z, a.w); o.z = pk2(b.x, b.y); o.w = pk2(b.z, b.w);
  *reinterpret_cast<uint4*>(xb1 + i) = o;
  a = *reinterpret_cast<const float4*>(x2 + i);
  b = *reinterpret_cast<const float4*>(x2 + i + 4);
  o.x = pk2(a.x, a.y); o.y = pk2(a.z, a.w); o.z = pk2(b.x, b.y); o.w = pk2(b.z, b.w);
  *reinterpret_cast<uint4*>(xb2 + i) = o;
}

// ---------- QKV GEMM: B-stationary (96KB LDS, full K), barrier-free K-loop ----------
// 256x128 tile, 8 waves (4M x 2N, 64x64 each). A direct global->reg (3-deep
// rotation), B conflict-free operand-order ds_read_b128. Barriers: 1 after
// B-fill, 1 before epilogue. Compiler manages all data waits (pure dataflow).
__global__ __launch_bounds__(512, 2) void gemm_qkv(
    const u16* __restrict__ xb1, const u16* __restrict__ xb2,
    const u16* __restrict__ wT, const float* __restrict__ bias,
    u16* __restrict__ q1, u16* __restrict__ k1, u16* __restrict__ v1,
    u16* __restrict__ k2, u16* __restrict__ v2)
{
  __shared__ __align__(16) u16 Bs[49152];   // 96KB: [8 fragcol][12 ks][512]; Cs alias in epilogue

  // bijective XCD-chunked swizzle: 5880 = 8 * 735 (735 = 49 mt x 15 nt)
  const int bid0 = blockIdx.x;
  const int lin = (bid0 & 7) * 735 + (bid0 >> 3);
  const int mt = lin / 15;                  // 0..391
  const int nt = lin - mt * 15;

  const bool isx2 = nt >= 9;
  const u16* __restrict__ X = isx2 ? xb2 : xb1;
  const int colbase = isx2 ? 384 + (nt - 9) * 128 : nt * 128;
  const int m0 = mt * 256;
  const int tid = threadIdx.x;
  const int lane = tid & 63, w = tid >> 6;
  const int wm = w & 3, wn = w >> 2;        // 4M x 2N wave grid
  const int l15 = lane & 15, l4 = lane >> 4;

  // ---- B fill: wave w fills frag-col j=w, all 12 ks blocks (12 gload16) ----
  {
    const u16* gbw = wT + (size_t)(colbase + w * 16 + l15) * CH + l4 * 8;
#pragma unroll
    for (int u = 0; u < 12; ++u)
      gload16(gbw + u * 32, &Bs[(w * 12 + u) * 512]);
  }
  __builtin_amdgcn_sched_barrier(0);

  // ---- A prologue: 3-deep register prefetch (12 dwordx4) ----
  const u16* gaw = X + (size_t)(m0 + wm * 64 + l15) * CH + l4 * 8;
  short8 areg[3][4];
#pragma unroll
  for (int pk = 0; pk < 3; ++pk)
#pragma unroll
    for (int i = 0; i < 4; ++i)
      areg[pk][i] = *reinterpret_cast<const short8*>(gaw + i * 16 * CH + pk * 32);

  asm volatile("s_waitcnt vmcnt(12)" ::: "memory");  // 12 B-fill done; 12 A-loads in flight
  __builtin_amdgcn_s_barrier();
  __builtin_amdgcn_sched_barrier(0);

  f32x4 acc[4][4] = {};
#pragma unroll
  for (int ks = 0; ks < 12; ++ks) {
    short8 bfr[4];
#pragma unroll
    for (int j = 0; j < 4; ++j)
      bfr[j] = *reinterpret_cast<const short8*>(&Bs[((wn * 4 + j) * 12 + ks) * 512 + lane * 8]);
#pragma unroll
    for (int i = 0; i < 4; ++i)
#pragma unroll
      for (int j = 0; j < 4; ++j)
        acc[i][j] = __builtin_amdgcn_mfma_f32_16x16x32_bf16(areg[ks % 3][i], bfr[j], acc[i][j], 0, 0, 0);
    if (ks + 3 < 12) {
#pragma unroll
      for (int i = 0; i < 4; ++i)
        areg[ks % 3][i] = *reinterpret_cast<const short8*>(gaw + i * 16 * CH + (ks + 3) * 32);
    }
  }

  // ---- epilogue: all B-reads done -> Cs aliases Bs ----
  asm volatile("s_waitcnt lgkmcnt(0)" ::: "memory");
  __builtin_amdgcn_s_barrier();
  u16* Cs = Bs;                             // [256][152] = 77824 B

#pragma unroll
  for (int j = 0; j < 4; ++j) {
    const int colL = wn * 64 + j * 16 + l15;
    const int gcol = colbase + colL;
    const float bb = bias[gcol];
    const float scl = (gcol < 384) ? SCALE_Q : 1.0f;
#pragma unroll
    for (int i = 0; i < 4; ++i)
#pragma unroll
      for (int r = 0; r < 4; ++r) {
        const int row = wm * 64 + i * 16 + l4 * 4 + r;
        Cs[row * 152 + (colL ^ (((row >> 2) & 3) << 3))] = f2bf((acc[i][j][r] + bb) * scl);
      }
  }
  __syncthreads();

  u16* dst;
  int tb;
  if (colbase < 384)      { dst = q1;              tb = colbase; }
  else if (colbase < 768) { dst = isx2 ? k2 : k1;  tb = colbase - 384; }
  else                    { dst = isx2 ? v2 : v1;  tb = colbase - 768; }

#pragma unroll
  for (int u = 0; u < 8; ++u) {
    const int pc = tid + u * 512;           // 0..4095
    const int row = pc >> 4, pp = pc & 15;
    const uint4 val = *reinterpret_cast<const uint4*>(&Cs[row * 152 + ((pp ^ ((row >> 2) & 3)) << 3)]);
    const int gm = m0 + row;
    const int b = gm / 49, tok = gm - b * 49;
    const int cm = tb + pp * 8;
    const int h = cm >> 5, d0 = cm & 31;
    *reinterpret_cast<uint4*>(&dst[(((size_t)b * NH + h) * NTOK + tok) * HD + d0]) = val;
  }
}

// ---------- attention: swapped QK^T (lane-local rows), float4 combined bias ----------
__global__ __launch_bounds__(256) void attn_kernel(
    const u16* __restrict__ q1, const u16* __restrict__ k1, const u16* __restrict__ v1,
    const u16* __restrict__ k2, const u16* __restrict__ v2,
    const float* __restrict__ comb, float* __restrict__ outw)
{
  __shared__ __align__(16) u16 VT[2][32][72];  // [half][d][tok], tok padded to 64 (49.. zeroed)
  __shared__ __align__(16) u16 Pb[4][2][512];  // [wave][kt][operand-order block]

  const int h = blockIdx.x, b = blockIdx.y;
  const int tid = threadIdx.x;
  const int lane = tid & 63, wt = tid >> 6;
  const int l15 = lane & 15, l4 = lane >> 4;
  const size_t base = ((size_t)b * NH + h) * 1568;

  // stage V: uint4 gather (8 d at fixed tok) -> transposed scatter into VT
  for (int e = tid; e < 392; e += 256) {
    const int p = e >= 196;
    const int e2 = e - p * 196;
    const int tok = e2 >> 2, d8 = (e2 & 3) * 8;
    const u16* src = (p ? v2 : v1) + base + tok * 32 + d8;
    uint4 val = *reinterpret_cast<const uint4*>(src);
    const u16* pv = reinterpret_cast<const u16*>(&val);
#pragma unroll
    for (int q = 0; q < 8; ++q) VT[p][d8 + q][tok] = pv[q];
  }
  // zero pad tok 49..63
  for (int e = tid; e < 2 * 32 * 15; e += 256) {
    int p = (e >= 480) ? 1 : 0;
    int e2 = e - p * 480;
    int d = e2 / 15, j = 49 + (e2 - d * 15);
    VT[p][d][j] = 0;
  }

  const short8 aq = *reinterpret_cast<const short8*>(&q1[base + (wt * 16 + l15) * 32 + l4 * 8]);

  __syncthreads();

  const int wb = b & 63;
  const int irow = wt * 16 + l15;
  const float* cb0 = comb + ((size_t)(wb * 12 + h) * 49 + (irow < 49 ? irow : 48)) * 52;
  const size_t obase = (size_t)b * (NTOK * 768) + (size_t)h * 32;

#pragma unroll
  for (int p = 0; p < 2; ++p) {
    const u16* __restrict__ kp = p ? k2 : k1;
    const float* cbp = cb0 + (size_t)p * TABF;

    // S^T = K @ Q^T : 4 j-tiles
    f32x4 st[4];
    __builtin_amdgcn_s_setprio(1);
#pragma unroll
    for (int jt = 0; jt < 4; ++jt) {
      short8 bk = *reinterpret_cast<const short8*>(&kp[base + (jt * 16 + l15) * 32 + l4 * 8]);
      st[jt] = __builtin_amdgcn_mfma_f32_16x16x32_bf16(bk, aq, (f32x4){0.f, 0.f, 0.f, 0.f}, 0, 0, 0);
    }
    __builtin_amdgcn_s_setprio(0);

    // bias (vector) + invalid-j kill
#pragma unroll
    for (int jt = 0; jt < 4; ++jt) {
      const float4 c = *reinterpret_cast<const float4*>(cbp + jt * 16 + l4 * 4);
#pragma unroll
      for (int r = 0; r < 4; ++r) {
        const int j = jt * 16 + l4 * 4 + r;
        st[jt][r] = (j < 49) ? st[jt][r] + (&c.x)[r] : -1e30f;
      }
    }

    // softmax over j (per-lane 16 values + reduce across l4 groups)
    float mx = -1e30f;
#pragma unroll
    for (int jt = 0; jt < 4; ++jt)
#pragma unroll
      for (int r = 0; r < 4; ++r) mx = fmaxf(mx, st[jt][r]);
    mx = fmaxf(mx, __shfl_xor(mx, 16));
    mx = fmaxf(mx, __shfl_xor(mx, 32));
    float sm = 0.f;
#pragma unroll
    for (int jt = 0; jt < 4; ++jt)
#pragma unroll
      for (int r = 0; r < 4; ++r) {
        float e = __expf(st[jt][r] - mx);
        st[jt][r] = e;
        sm += e;
      }
    sm += __shfl_xor(sm, 16);
    sm += __shfl_xor(sm, 32);
    const float si = 1.f / sm;

    // P^T -> operand-order LDS (paired u32 stores), wave-private
#pragma unroll
    for (int jt = 0; jt < 4; ++jt) {
      const int kt = jt >> 1;
#pragma unroll
      for (int r = 0; r < 4; r += 2) {
        const u32 pkv = pk2(st[jt][r] * si, st[jt][r + 1] * si);
        const int jrel = (jt & 1) * 16 + l4 * 4 + r;
        const int off = ((jrel >> 3) << 7) + l15 * 8 + (jrel & 7);
        *reinterpret_cast<u32*>(&Pb[wt][kt][off]) = pkv;
      }
    }

    // O = P @ V
    f32x4 o[2] = {};
    __builtin_amdgcn_s_setprio(1);
#pragma unroll
    for (int kt = 0; kt < 2; ++kt) {
      short8 ap = *reinterpret_cast<const short8*>(&Pb[wt][kt][lane * 8]);
#pragma unroll
      for (int n2 = 0; n2 < 2; ++n2) {
        short8 bvf = *reinterpret_cast<const short8*>(&VT[p][n2 * 16 + l15][kt * 32 + l4 * 8]);
        o[n2] = __builtin_amdgcn_mfma_f32_16x16x32_bf16(ap, bvf, o[n2], 0, 0, 0);
      }
    }
    __builtin_amdgcn_s_setprio(0);

#pragma unroll
    for (int n2 = 0; n2 < 2; ++n2)
#pragma unroll
      for (int r = 0; r < 4; ++r) {
        const int i = wt * 16 + l4 * 4 + r;
        if (i < 49)
          outw[obase + (size_t)i * 768 + p * 384 + n2 * 16 + l15] = o[n2][r];
      }
  }
}

// ---------- proj GEMM: BK=32, 32KB LDS; A(f32) reg-staged, B via gload_lds ----------
__global__ __launch_bounds__(256) void gemm_proj(
    const float* __restrict__ Wsrc, const u16* __restrict__ wT,
    const float* __restrict__ bias, float* __restrict__ outx)
{
  __shared__ __align__(16) u16 smem[16384];   // 32768 B
  // bijective XCD-chunked swizzle: 2352 = 8 * 294
  const int bid0 = blockIdx.x;
  const int lin = (bid0 & 7) * 294 + (bid0 >> 3);
  const int mt = lin / 3;
  const int nt = lin - mt * 3;

  const int colbase = nt * 128;
  const int m0 = mt * 128;
  const int tid = threadIdx.x;
  const int lane = tid & 63, wv = tid >> 6;
  const int wr = wv >> 1, wc = wv & 1;
  const int l15 = lane & 15, l4 = lane >> 4;

  f32x4 acc[4][4] = {};

  const float* ga = Wsrc + (size_t)(m0 + l15) * 768 + l4 * 8;
  const u16*   gb = wT + (size_t)(colbase + l15) * CH + l4 * 8;
  const int g0 = wv, g1 = wv + 4;

  float4 ar0[2][2], ar1[2][2];
  auto loadA = [&](float4 (*ar)[2], int kk) {
    ar[0][0] = *reinterpret_cast<const float4*>(ga + kk + g0 * 16 * 768);
    ar[0][1] = *reinterpret_cast<const float4*>(ga + kk + g0 * 16 * 768 + 4);
    ar[1][0] = *reinterpret_cast<const float4*>(ga + kk + g1 * 16 * 768);
    ar[1][1] = *reinterpret_cast<const float4*>(ga + kk + g1 * 16 * 768 + 4);
  };
  auto stageB = [&](int bs, int kk) {
    u16* B = smem + bs * 8192 + 4096;
    gload16(gb + kk + g0 * 16 * CH, B + g0 * 512);
    gload16(gb + kk + g1 * 16 * CH, B + g1 * 512);
  };
  auto writeA = [&](float4 (*ar)[2], int bs) {
    u16* A = smem + bs * 8192;
    uint4 v;
    v.x = pk2(ar[0][0].x, ar[0][0].y); v.y = pk2(ar[0][0].z, ar[0][0].w);
    v.z = pk2(ar[0][1].x, ar[0][1].y); v.w = pk2(ar[0][1].z, ar[0][1].w);
    *reinterpret_cast<uint4*>(&A[g0 * 512 + lane * 8]) = v;
    v.x = pk2(ar[1][0].x, ar[1][0].y); v.y = pk2(ar[1][0].z, ar[1][0].w);
    v.z = pk2(ar[1][1].x, ar[1][1].y); v.w = pk2(ar[1][1].z, ar[1][1].w);
    *reinterpret_cast<uint4*>(&A[g1 * 512 + lane * 8]) = v;
  };

  loadA(ar0, 0);  stageB(0, 0);     // 6 VMEM
  loadA(ar1, 32); stageB(1, 32);    // -> 12 outstanding

#pragma unroll
  for (int k = 0; k < 12; ++k) {
    if (k < 11) asm volatile("s_waitcnt vmcnt(6)" ::: "memory");   // stage(k) done, stage(k+1) in flight
    else        asm volatile("s_waitcnt vmcnt(0)" ::: "memory");
    const int cb = k & 1;
    if (cb == 0) writeA(ar0, 0); else writeA(ar1, 1);
    asm volatile("s_waitcnt lgkmcnt(0)" ::: "memory");
    __builtin_amdgcn_s_barrier();
    __builtin_amdgcn_sched_barrier(0);
    const u16* A = smem + cb * 8192;
    const u16* B = A + 4096;
    short8 af[4], bfr[4];
#pragma unroll
    for (int i = 0; i < 4; ++i)
      af[i] = *reinterpret_cast<const short8*>(&A[(wr * 4 + i) * 512 + lane * 8]);
#pragma unroll
    for (int j = 0; j < 4; ++j)
      bfr[j] = *reinterpret_cast<const short8*>(&B[(wc * 4 + j) * 512 + lane * 8]);
#pragma unroll
    for (int i = 0; i < 4; ++i)
#pragma unroll
      for (int j = 0; j < 4; ++j)
        acc[i][j] = __builtin_amdgcn_mfma_f32_16x16x32_bf16(af[i], bfr[j], acc[i][j], 0, 0, 0);
    asm volatile("s_waitcnt lgkmcnt(0)" ::: "memory");
    __builtin_amdgcn_s_barrier();
    __builtin_amdgcn_sched_barrier(0);
    if (k + 2 < 12) {
      if (cb == 0) loadA(ar0, (k + 2) * 32); else loadA(ar1, (k + 2) * 32);
      stageB(cb, (k + 2) * 32);
    }
  }

#pragma unroll
  for (int j = 0; j < 4; ++j) {
    const int col = colbase + wc * 64 + j * 16 + l15;
    const float bb = bias[col];
#pragma unroll
    for (int i = 0; i < 4; ++i) {
#pragma unroll
      for (int r = 0; r < 4; ++r) {
        const int gm = m0 + wr * 64 + i * 16 + l4 * 4 + r;
        outx[(size_t)gm * CH + col] = acc[i][j][r] + bb;
      }
    }
  }
}

extern "C" void kernel_launch(void* const* d_in, const int* in_sizes, int n_in,
                              void* d_out, int out_size, void* d_ws, size_t ws_size,
                              hipStream_t stream) {
  const float* x1        = (const float*)d_in[0];
  const float* x2        = (const float*)d_in[1];
  const float* mask1     = (const float*)d_in[2];
  const float* mask2     = (const float*)d_in[3];
  const float* w_qkv     = (const float*)d_in[4];
  const float* b_qkv     = (const float*)d_in[5];
  const float* w_proj    = (const float*)d_in[6];
  const float* b_proj    = (const float*)d_in[7];
  const float* rpb_table = (const float*)d_in[8];
  const int*   rel_index = (const int*)d_in[9];

  float* outx = (float*)d_out;                      // [2048,49,384] f32
  const size_t SZe = (size_t)NB * NH * NTOK * HD;   // 38,535,168 elements
  float* outw = outx + SZe;                         // [2048,49,768] f32

  // q1,k1 (bf16) live in the x-region of d_out; proj writes x last.
  u16* q1 = (u16*)d_out;
  u16* k1 = q1 + SZe;
  // xb1,xb2 (bf16 copies of x1,x2) live in the outw region; attn overwrites later.
  u16* xb1 = (u16*)outw;
  u16* xb2 = xb1 + SZe;

  u16* v1 = (u16*)d_ws;
  u16* k2 = v1 + SZe;
  u16* v2 = k2 + SZe;
  u16* wqkvT  = v2 + SZe;              // [1152][384] bf16
  u16* wprojT = wqkvT + 1152 * 384;    // [384][384] bf16
  float* comb = (float*)(wprojT + 384 * 384);  // 2 x [64][12][49][52] f32 = 15.7MB

  prep_w<<<2304, 256, 0, stream>>>(w_qkv, w_proj, wqkvT, wprojT);
  prep_c<<<768, 256, 0, stream>>>(rpb_table, rel_index, mask1, mask2, comb);
  conv_bf16<<<(int)(SZe / (256 * 8)), 256, 0, stream>>>(x1, x2, xb1, xb2);
  gemm_qkv<<<5880, 512, 0, stream>>>(xb1, xb2, wqkvT, b_qkv, q1, k1, v1, k2, v2);
  attn_kernel<<<dim3(12, 2048), 256, 0, stream>>>(q1, k1, v1, k2, v2, comb, outw);
  gemm_proj<<<2352, 256, 0, stream>>>(outw, wprojT, b_proj, outx);
}

// Round 10
// 716.234 us; speedup vs baseline: 1.1415x; 1.1415x over previous
//
#include <hip/hip_runtime.h>

typedef unsigned short u16;
typedef unsigned int u32;
typedef __attribute__((ext_vector_type(8))) short short8;
typedef __attribute__((ext_vector_type(4))) float f32x4;

#define NB 2048
#define NTOK 49
#define CH 384
#define NH 12
#define HD 32
#define SCALE_Q 0.17677669529663687f
#define TABF 1956864   // 768 * 49 * 52

__device__ __forceinline__ u16 f2bf(float f) {
  u32 u = __float_as_uint(f);
  u += 0x7fffu + ((u >> 16) & 1u);
  return (u16)(u >> 16);
}
__device__ __forceinline__ float bf2f(u16 h) { return __uint_as_float(((u32)h) << 16); }
__device__ __forceinline__ u32 pk2(float a, float b) { return (u32)f2bf(a) | ((u32)f2bf(b) << 16); }

// async global->LDS, 16B per lane, LDS dest = wave-uniform base + lane*16
__device__ __forceinline__ void gload16(const u16* g, u16* l) {
  __builtin_amdgcn_global_load_lds(
      (const __attribute__((address_space(1))) u32*)g,
      (__attribute__((address_space(3))) u32*)l,
      16, 0, 0);
}

// ---------- prep_w: transpose weights to bf16 ----------
__global__ void prep_w(const float* __restrict__ w_qkv, const float* __restrict__ w_proj,
                       u16* __restrict__ wqkvT, u16* __restrict__ wprojT)
{
  int idx = blockIdx.x * 256 + threadIdx.x;
  if (idx < 1152 * 384) {
    int n = idx / 384, k = idx - n * 384;
    wqkvT[idx] = f2bf(w_qkv[(size_t)k * 1152 + n]);
  } else if (idx < 1152 * 384 + 384 * 384) {
    int i2 = idx - 1152 * 384;
    int n = i2 / 384, k = i2 - n * 384;
    wprojT[i2] = f2bf(w_proj[(size_t)k * 384 + n]);
  }
}

// ---------- prep_c: combined bias tables comb[p][wb][h][i][52] = rpb + mask ----------
__global__ __launch_bounds__(256) void prep_c(const float* __restrict__ rpb_table,
                                              const int* __restrict__ rel_index,
                                              const float* __restrict__ mask1,
                                              const float* __restrict__ mask2,
                                              float* __restrict__ comb)
{
  const int wbh = blockIdx.x;            // 0..767 = wb*12 + h
  const int wb = wbh / 12, h = wbh - wb * 12;
  const size_t ob = (size_t)wbh * (49 * 52);
  for (int r = threadIdx.x; r < 2401; r += 256) {
    int i = r / 49, j = r - i * 49;
    float rv = rpb_table[(size_t)rel_index[r] * 12 + h];
    comb[ob + i * 52 + j]        = rv + mask1[(size_t)wb * 2401 + r];
    comb[TABF + ob + i * 52 + j] = rv + mask2[(size_t)wb * 2401 + r];
  }
}

// ---------- convert x1,x2 f32 -> bf16 (8 elems/thread) ----------
__global__ __launch_bounds__(256) void conv_bf16(const float* __restrict__ x1, const float* __restrict__ x2,
                                                 u16* __restrict__ xb1, u16* __restrict__ xb2)
{
  const size_t i = ((size_t)blockIdx.x * 256 + threadIdx.x) * 8;
  float4 a = *reinterpret_cast<const float4*>(x1 + i);
  float4 b = *reinterpret_cast<const float4*>(x1 + i + 4);
  uint4 o;
  o.x = pk2(a.x, a.y); o.y = pk2(a.z, a.w); o.z = pk2(b.x, b.y); o.w = pk2(b.z, b.w);
  *reinterpret_cast<uint4*>(xb1 + i) = o;
  a = *reinterpret_cast<const float4*>(x2 + i);
  b = *reinterpret_cast<const float4*>(x2 + i + 4);
  o.x = pk2(a.x, a.y); o.y = pk2(a.z, a.w); o.z = pk2(b.x, b.y); o.w = pk2(b.z, b.w);
  *reinterpret_cast<uint4*>(xb2 + i) = o;
}

// ---------- QKV GEMM: 256x128 tile, BK=32, 8 waves, counted-vmcnt pipeline ----------
// 2 blocks/CU (77.8KB LDS incl. epilogue alias). Per wave per step: 2 A + 1 B
// gload16 (vmcnt(3) = one stage in flight), 16 MFMA. Buffers at smem+bs*12288.
__global__ __launch_bounds__(512) void gemm_qkv(
    const u16* __restrict__ xb1, const u16* __restrict__ xb2,
    const u16* __restrict__ wT, const float* __restrict__ bias,
    u16* __restrict__ q1, u16* __restrict__ k1, u16* __restrict__ v1,
    u16* __restrict__ k2, u16* __restrict__ v2)
{
  __shared__ __align__(16) u16 smem[38912];   // 77824 B (epilogue Cs [256][152])
  u16* Cs = smem;

  // bijective XCD-chunked swizzle: 5880 = 8 * 735 (735 = 49 mt x 15 nt)
  const int bid0 = blockIdx.x;
  const int lin = (bid0 & 7) * 735 + (bid0 >> 3);
  const int mt = lin / 15;                  // 0..391
  const int nt = lin - mt * 15;

  const bool isx2 = nt >= 9;
  const u16* __restrict__ X = isx2 ? xb2 : xb1;
  const int colbase = isx2 ? 384 + (nt - 9) * 128 : nt * 128;
  const int m0 = mt * 256;
  const int tid = threadIdx.x;
  const int lane = tid & 63, w = tid >> 6;
  const int wm = w & 3, wn = w >> 2;        // 4M x 2N wave grid, 64x64 each
  const int l15 = lane & 15, l4 = lane >> 4;

  f32x4 acc[4][4] = {};

  const u16* ga = X + (size_t)(m0 + l15) * CH + l4 * 8;
  const u16* gb = wT + (size_t)(colbase + w * 16 + l15) * CH + l4 * 8;
  const int ga0 = (2 * w) * 16 * CH, ga1 = (2 * w + 1) * 16 * CH;

  auto stage = [&](int bs, int kk) {
    u16* A = smem + bs * 12288;
    u16* B = A + 8192;
    gload16(ga + kk + ga0, &A[(2 * w) * 512]);
    gload16(ga + kk + ga1, &A[(2 * w + 1) * 512]);
    gload16(gb + kk, &B[w * 512]);
  };

  stage(0, 0);
  stage(1, 32);

#pragma unroll
  for (int k = 0; k < 12; ++k) {
    if (k < 11) asm volatile("s_waitcnt vmcnt(3)" ::: "memory");   // stage(k) done, stage(k+1) in flight
    else        asm volatile("s_waitcnt vmcnt(0)" ::: "memory");
    __builtin_amdgcn_s_barrier();
    __builtin_amdgcn_sched_barrier(0);
    const int cb = k & 1;
    const u16* A = smem + cb * 12288;
    const u16* B = A + 8192;
    short8 af[4], bfr[4];
#pragma unroll
    for (int i = 0; i < 4; ++i)
      af[i] = *reinterpret_cast<const short8*>(&A[(wm * 4 + i) * 512 + lane * 8]);
#pragma unroll
    for (int j = 0; j < 4; ++j)
      bfr[j] = *reinterpret_cast<const short8*>(&B[(wn * 4 + j) * 512 + lane * 8]);
#pragma unroll
    for (int i = 0; i < 4; ++i)
#pragma unroll
      for (int j = 0; j < 4; ++j)
        acc[i][j] = __builtin_amdgcn_mfma_f32_16x16x32_bf16(af[i], bfr[j], acc[i][j], 0, 0, 0);
    asm volatile("s_waitcnt lgkmcnt(0)" ::: "memory");
    __builtin_amdgcn_s_barrier();
    __builtin_amdgcn_sched_barrier(0);
    if (k + 2 < 12) stage(cb, (k + 2) * 32);   // refill freed buffer; stays in flight across barriers
  }

  // ---- epilogue: bias+scale+pack into LDS, then coalesced 16B writes ----
#pragma unroll
  for (int j = 0; j < 4; ++j) {
    const int colL = wn * 64 + j * 16 + l15;
    const int gcol = colbase + colL;
    const float bb = bias[gcol];
    const float scl = (gcol < 384) ? SCALE_Q : 1.0f;
#pragma unroll
    for (int i = 0; i < 4; ++i)
#pragma unroll
      for (int r = 0; r < 4; ++r) {
        const int row = wm * 64 + i * 16 + l4 * 4 + r;
        Cs[row * 152 + (colL ^ (((row >> 2) & 3) << 3))] = f2bf((acc[i][j][r] + bb) * scl);
      }
  }
  __syncthreads();

  u16* dst;
  int tb;
  if (colbase < 384)      { dst = q1;              tb = colbase; }
  else if (colbase < 768) { dst = isx2 ? k2 : k1;  tb = colbase - 384; }
  else                    { dst = isx2 ? v2 : v1;  tb = colbase - 768; }

#pragma unroll
  for (int u = 0; u < 8; ++u) {
    const int pc = tid + u * 512;           // 0..4095
    const int row = pc >> 4, pp = pc & 15;
    const uint4 val = *reinterpret_cast<const uint4*>(&Cs[row * 152 + ((pp ^ ((row >> 2) & 3)) << 3)]);
    const int gm = m0 + row;
    const int b = gm / 49, tok = gm - b * 49;
    const int cm = tb + pp * 8;
    const int h = cm >> 5, d0 = cm & 31;
    *reinterpret_cast<uint4*>(&dst[(((size_t)b * NH + h) * NTOK + tok) * HD + d0]) = val;
  }
}

// ---------- attention: swapped QK^T (lane-local rows), float4 combined bias ----------
__global__ __launch_bounds__(256) void attn_kernel(
    const u16* __restrict__ q1, const u16* __restrict__ k1, const u16* __restrict__ v1,
    const u16* __restrict__ k2, const u16* __restrict__ v2,
    const float* __restrict__ comb, float* __restrict__ outw)
{
  __shared__ __align__(16) u16 VT[2][32][72];  // [half][d][tok], tok padded to 64 (49.. zeroed)
  __shared__ __align__(16) u16 Pb[4][2][512];  // [wave][kt][operand-order block]

  const int h = blockIdx.x, b = blockIdx.y;
  const int tid = threadIdx.x;
  const int lane = tid & 63, wt = tid >> 6;
  const int l15 = lane & 15, l4 = lane >> 4;
  const size_t base = ((size_t)b * NH + h) * 1568;

  // stage V: uint4 gather (8 d at fixed tok) -> transposed scatter into VT
  for (int e = tid; e < 392; e += 256) {
    const int p = e >= 196;
    const int e2 = e - p * 196;
    const int tok = e2 >> 2, d8 = (e2 & 3) * 8;
    const u16* src = (p ? v2 : v1) + base + tok * 32 + d8;
    uint4 val = *reinterpret_cast<const uint4*>(src);
    const u16* pv = reinterpret_cast<const u16*>(&val);
#pragma unroll
    for (int q = 0; q < 8; ++q) VT[p][d8 + q][tok] = pv[q];
  }
  // zero pad tok 49..63
  for (int e = tid; e < 2 * 32 * 15; e += 256) {
    int p = (e >= 480) ? 1 : 0;
    int e2 = e - p * 480;
    int d = e2 / 15, j = 49 + (e2 - d * 15);
    VT[p][d][j] = 0;
  }

  const short8 aq = *reinterpret_cast<const short8*>(&q1[base + (wt * 16 + l15) * 32 + l4 * 8]);

  __syncthreads();

  const int wb = b & 63;
  const int irow = wt * 16 + l15;
  const float* cb0 = comb + ((size_t)(wb * 12 + h) * 49 + (irow < 49 ? irow : 48)) * 52;
  const size_t obase = (size_t)b * (NTOK * 768) + (size_t)h * 32;

#pragma unroll
  for (int p = 0; p < 2; ++p) {
    const u16* __restrict__ kp = p ? k2 : k1;
    const float* cbp = cb0 + (size_t)p * TABF;

    // S^T = K @ Q^T : 4 j-tiles
    f32x4 st[4];
    __builtin_amdgcn_s_setprio(1);
#pragma unroll
    for (int jt = 0; jt < 4; ++jt) {
      short8 bk = *reinterpret_cast<const short8*>(&kp[base + (jt * 16 + l15) * 32 + l4 * 8]);
      st[jt] = __builtin_amdgcn_mfma_f32_16x16x32_bf16(bk, aq, (f32x4){0.f, 0.f, 0.f, 0.f}, 0, 0, 0);
    }
    __builtin_amdgcn_s_setprio(0);

    // bias (vector) + invalid-j kill
#pragma unroll
    for (int jt = 0; jt < 4; ++jt) {
      const float4 c = *reinterpret_cast<const float4*>(cbp + jt * 16 + l4 * 4);
#pragma unroll
      for (int r = 0; r < 4; ++r) {
        const int j = jt * 16 + l4 * 4 + r;
        st[jt][r] = (j < 49) ? st[jt][r] + (&c.x)[r] : -1e30f;
      }
    }

    // softmax over j (per-lane 16 values + reduce across l4 groups)
    float mx = -1e30f;
#pragma unroll
    for (int jt = 0; jt < 4; ++jt)
#pragma unroll
      for (int r = 0; r < 4; ++r) mx = fmaxf(mx, st[jt][r]);
    mx = fmaxf(mx, __shfl_xor(mx, 16));
    mx = fmaxf(mx, __shfl_xor(mx, 32));
    float sm = 0.f;
#pragma unroll
    for (int jt = 0; jt < 4; ++jt)
#pragma unroll
      for (int r = 0; r < 4; ++r) {
        float e = __expf(st[jt][r] - mx);
        st[jt][r] = e;
        sm += e;
      }
    sm += __shfl_xor(sm, 16);
    sm += __shfl_xor(sm, 32);
    const float si = 1.f / sm;

    // P^T -> operand-order LDS (paired u32 stores), wave-private
#pragma unroll
    for (int jt = 0; jt < 4; ++jt) {
      const int kt = jt >> 1;
#pragma unroll
      for (int r = 0; r < 4; r += 2) {
        const u32 pkv = pk2(st[jt][r] * si, st[jt][r + 1] * si);
        const int jrel = (jt & 1) * 16 + l4 * 4 + r;
        const int off = ((jrel >> 3) << 7) + l15 * 8 + (jrel & 7);
        *reinterpret_cast<u32*>(&Pb[wt][kt][off]) = pkv;
      }
    }

    // O = P @ V
    f32x4 o[2] = {};
    __builtin_amdgcn_s_setprio(1);
#pragma unroll
    for (int kt = 0; kt < 2; ++kt) {
      short8 ap = *reinterpret_cast<const short8*>(&Pb[wt][kt][lane * 8]);
#pragma unroll
      for (int n2 = 0; n2 < 2; ++n2) {
        short8 bvf = *reinterpret_cast<const short8*>(&VT[p][n2 * 16 + l15][kt * 32 + l4 * 8]);
        o[n2] = __builtin_amdgcn_mfma_f32_16x16x32_bf16(ap, bvf, o[n2], 0, 0, 0);
      }
    }
    __builtin_amdgcn_s_setprio(0);

#pragma unroll
    for (int n2 = 0; n2 < 2; ++n2)
#pragma unroll
      for (int r = 0; r < 4; ++r) {
        const int i = wt * 16 + l4 * 4 + r;
        if (i < 49)
          outw[obase + (size_t)i * 768 + p * 384 + n2 * 16 + l15] = o[n2][r];
      }
  }
}

// ---------- proj GEMM: BK=32, 32KB LDS; A(f32) reg-staged, B via gload_lds ----------
__global__ __launch_bounds__(256) void gemm_proj(
    const float* __restrict__ Wsrc, const u16* __restrict__ wT,
    const float* __restrict__ bias, float* __restrict__ outx)
{
  __shared__ __align__(16) u16 smem[16384];   // 32768 B
  // bijective XCD-chunked swizzle: 2352 = 8 * 294
  const int bid0 = blockIdx.x;
  const int lin = (bid0 & 7) * 294 + (bid0 >> 3);
  const int mt = lin / 3;
  const int nt = lin - mt * 3;

  const int colbase = nt * 128;
  const int m0 = mt * 128;
  const int tid = threadIdx.x;
  const int lane = tid & 63, wv = tid >> 6;
  const int wr = wv >> 1, wc = wv & 1;
  const int l15 = lane & 15, l4 = lane >> 4;

  f32x4 acc[4][4] = {};

  const float* ga = Wsrc + (size_t)(m0 + l15) * 768 + l4 * 8;
  const u16*   gb = wT + (size_t)(colbase + l15) * CH + l4 * 8;
  const int g0 = wv, g1 = wv + 4;

  float4 ar0[2][2], ar1[2][2];
  auto loadA = [&](float4 (*ar)[2], int kk) {
    ar[0][0] = *reinterpret_cast<const float4*>(ga + kk + g0 * 16 * 768);
    ar[0][1] = *reinterpret_cast<const float4*>(ga + kk + g0 * 16 * 768 + 4);
    ar[1][0] = *reinterpret_cast<const float4*>(ga + kk + g1 * 16 * 768);
    ar[1][1] = *reinterpret_cast<const float4*>(ga + kk + g1 * 16 * 768 + 4);
  };
  auto stageB = [&](int bs, int kk) {
    u16* B = smem + bs * 8192 + 4096;
    gload16(gb + kk + g0 * 16 * CH, B + g0 * 512);
    gload16(gb + kk + g1 * 16 * CH, B + g1 * 512);
  };
  auto writeA = [&](float4 (*ar)[2], int bs) {
    u16* A = smem + bs * 8192;
    uint4 v;
    v.x = pk2(ar[0][0].x, ar[0][0].y); v.y = pk2(ar[0][0].z, ar[0][0].w);
    v.z = pk2(ar[0][1].x, ar[0][1].y); v.w = pk2(ar[0][1].z, ar[0][1].w);
    *reinterpret_cast<uint4*>(&A[g0 * 512 + lane * 8]) = v;
    v.x = pk2(ar[1][0].x, ar[1][0].y); v.y = pk2(ar[1][0].z, ar[1][0].w);
    v.z = pk2(ar[1][1].x, ar[1][1].y); v.w = pk2(ar[1][1].z, ar[1][1].w);
    *reinterpret_cast<uint4*>(&A[g1 * 512 + lane * 8]) = v;
  };

  loadA(ar0, 0);  stageB(0, 0);     // 6 VMEM
  loadA(ar1, 32); stageB(1, 32);    // -> 12 outstanding

#pragma unroll
  for (int k = 0; k < 12; ++k) {
    if (k < 11) asm volatile("s_waitcnt vmcnt(6)" ::: "memory");   // stage(k) done, stage(k+1) in flight
    else        asm volatile("s_waitcnt vmcnt(0)" ::: "memory");
    const int cb = k & 1;
    if (cb == 0) writeA(ar0, 0); else writeA(ar1, 1);
    asm volatile("s_waitcnt lgkmcnt(0)" ::: "memory");
    __builtin_amdgcn_s_barrier();
    __builtin_amdgcn_sched_barrier(0);
    const u16* A = smem + cb * 8192;
    const u16* B = A + 4096;
    short8 af[4], bfr[4];
#pragma unroll
    for (int i = 0; i < 4; ++i)
      af[i] = *reinterpret_cast<const short8*>(&A[(wr * 4 + i) * 512 + lane * 8]);
#pragma unroll
    for (int j = 0; j < 4; ++j)
      bfr[j] = *reinterpret_cast<const short8*>(&B[(wc * 4 + j) * 512 + lane * 8]);
#pragma unroll
    for (int i = 0; i < 4; ++i)
#pragma unroll
      for (int j = 0; j < 4; ++j)
        acc[i][j] = __builtin_amdgcn_mfma_f32_16x16x32_bf16(af[i], bfr[j], acc[i][j], 0, 0, 0);
    asm volatile("s_waitcnt lgkmcnt(0)" ::: "memory");
    __builtin_amdgcn_s_barrier();
    __builtin_amdgcn_sched_barrier(0);
    if (k + 2 < 12) {
      if (cb == 0) loadA(ar0, (k + 2) * 32); else loadA(ar1, (k + 2) * 32);
      stageB(cb, (k + 2) * 32);
    }
  }

#pragma unroll
  for (int j = 0; j < 4; ++j) {
    const int col = colbase + wc * 64 + j * 16 + l15;
    const float bb = bias[col];
#pragma unroll
    for (int i = 0; i < 4; ++i) {
#pragma unroll
      for (int r = 0; r < 4; ++r) {
        const int gm = m0 + wr * 64 + i * 16 + l4 * 4 + r;
        outx[(size_t)gm * CH + col] = acc[i][j][r] + bb;
      }
    }
  }
}

extern "C" void kernel_launch(void* const* d_in, const int* in_sizes, int n_in,
                              void* d_out, int out_size, void* d_ws, size_t ws_size,
                              hipStream_t stream) {
  const float* x1        = (const float*)d_in[0];
  const float* x2        = (const float*)d_in[1];
  const float* mask1     = (const float*)d_in[2];
  const float* mask2     = (const float*)d_in[3];
  const float* w_qkv     = (const float*)d_in[4];
  const float* b_qkv     = (const float*)d_in[5];
  const float* w_proj    = (const float*)d_in[6];
  const float* b_proj    = (const float*)d_in[7];
  const float* rpb_table = (const float*)d_in[8];
  const int*   rel_index = (const int*)d_in[9];

  float* outx = (float*)d_out;                      // [2048,49,384] f32
  const size_t SZe = (size_t)NB * NH * NTOK * HD;   // 38,535,168 elements
  float* outw = outx + SZe;                         // [2048,49,768] f32

  // q1,k1 (bf16) live in the x-region of d_out; proj writes x last.
  u16* q1 = (u16*)d_out;
  u16* k1 = q1 + SZe;
  // xb1,xb2 (bf16 copies of x1,x2) live in the outw region; attn overwrites later.
  u16* xb1 = (u16*)outw;
  u16* xb2 = xb1 + SZe;

  u16* v1 = (u16*)d_ws;
  u16* k2 = v1 + SZe;
  u16* v2 = k2 + SZe;
  u16* wqkvT  = v2 + SZe;              // [1152][384] bf16
  u16* wprojT = wqkvT + 1152 * 384;    // [384][384] bf16
  float* comb = (float*)(wprojT + 384 * 384);  // 2 x [64][12][49][52] f32 = 15.7MB

  prep_w<<<2304, 256, 0, stream>>>(w_qkv, w_proj, wqkvT, wprojT);
  prep_c<<<768, 256, 0, stream>>>(rpb_table, rel_index, mask1, mask2, comb);
  conv_bf16<<<(int)(SZe / (256 * 8)), 256, 0, stream>>>(x1, x2, xb1, xb2);
  gemm_qkv<<<5880, 512, 0, stream>>>(xb1, xb2, wqkvT, b_qkv, q1, k1, v1, k2, v2);
  attn_kernel<<<dim3(12, 2048), 256, 0, stream>>>(q1, k1, v1, k2, v2, comb, outw);
  gemm_proj<<<2352, 256, 0, stream>>>(outw, wprojT, b_proj, outx);
}